// Round 14
// baseline (168.895 us; speedup 1.0000x reference)
//
#include <hip/hip_runtime.h>
#include <math.h>

// ---- problem constants ----
#define NN      4096   // nodes
#define INF_    512    // in features
#define OUTF    256    // out features
#define NHEAD   4
#define HDIM    64
#define KSPLIT  8

typedef __attribute__((ext_vector_type(8))) short  short8x;
typedef __attribute__((ext_vector_type(4))) float  float4x;
typedef __attribute__((ext_vector_type(2))) float  float2x;

__device__ __forceinline__ unsigned short f2bf(float x) {
    union { float f; unsigned int u; } c; c.f = x;
    unsigned int r = (c.u + 0x7FFFu + ((c.u >> 16) & 1u)) >> 16;
    return (unsigned short)r;
}
// pack 2 fp32 -> 2 bf16 in one dword (RNE, identical to f2bf)
__device__ __forceinline__ unsigned int cvtpk_bf16(float lo, float hi) {
    unsigned int r;
    asm("v_cvt_pk_bf16_f32 %0, %1, %2" : "=v"(r) : "v"(lo), "v"(hi));
    return r;
}
// unpack a bf16 pair (one dword) into float2 {lo, hi}
__device__ __forceinline__ float2x bf2up(unsigned int u) {
    union { unsigned int x; float f; } lo, hi;
    lo.x = u << 16; hi.x = u & 0xFFFF0000u;
    float2x r; r[0] = lo.f; r[1] = hi.f; return r;
}
__device__ __forceinline__ float2x max2(float2x a, float2x b) {
    float2x r; r[0] = fmaxf(a[0], b[0]); r[1] = fmaxf(a[1], b[1]); return r;
}

// ============================================================
// K1: blocks 0..255: h = feat @ W^T (fp32 converted in-register),
// 16-row tiles, BK=64, pitch 72; bias-inits the block's out slab.
// hT is written in B-FRAGMENT-MAJOR layout hTf:
//   short idx = ((n16*128 + kb2)*64 + quadB*16 + lidx)*8 + e
// so k_out_gemm's B loads are 1KB-contiguous per wave (no LDS).
// Epilogue also writes es/Bt/Dt.
// Blocks 256..2303: adj -> 16-bit masks (2 rows/block), packed in
// k_attn's consumption order. adj read exactly ONCE per launch.
// ============================================================
__global__ __launch_bounds__(256) void k_hedge(const float* __restrict__ feat,
                                               const float* __restrict__ W,
                                               const float* __restrict__ a,
                                               const float* __restrict__ bias,
                                               const float* __restrict__ adj,
                                               unsigned short* __restrict__ hTf,
                                               float* __restrict__ es,
                                               unsigned short* __restrict__ Bt,
                                               unsigned short* __restrict__ Dt,
                                               unsigned short* __restrict__ mask,
                                               float* __restrict__ out) {
    __shared__ __align__(16) unsigned short lds_f[16 * 72];
    __shared__ __align__(16) unsigned short lds_w[256 * 72];
    const int tid  = threadIdx.x;

    if (blockIdx.x >= 256) {
        // ---- mask production: 2 adj rows per block, coalesced ----
        const int mb = blockIdx.x - 256;        // 0..2047
        #pragma unroll
        for (int r = 0; r < 2; ++r) {
            const int row = mb * 2 + r;
            const float4x* arow4 = (const float4x*)(adj + (size_t)row * NN);
            unsigned int bits = 0;
            #pragma unroll
            for (int t = 0; t < 4; ++t) {
                float4x av = arow4[t * 256 + tid];
                #pragma unroll
                for (int e = 0; e < 4; ++e)
                    bits |= (av[e] > 0.1f ? 1u : 0u) << (t * 4 + e);
            }
            mask[(size_t)row * 256 + tid] = (unsigned short)bits;
        }
        return;
    }

    const int w    = tid >> 6;
    const int lane = tid & 63;
    const int lidx = lane & 15;
    const int quad = lane >> 4;
    const int i0   = blockIdx.x * 16;

    // ---- bias-init out rows i0..i0+15 (4096 floats, coalesced) ----
    {
        float4x bv = *(const float4x*)(bias + ((tid * 4) & 255));
        float* ob = out + (size_t)i0 * OUTF;
        #pragma unroll
        for (int itr = 0; itr < 4; ++itr)
            *(float4x*)(ob + itr * 1024 + tid * 4) = bv;
    }

    const int fr = tid >> 4;          // feat row 0..15
    const int fc = (tid & 15) * 4;    // feat k-chunk
    const int wr = tid >> 2;          // W row-within-group 0..63
    const int wc = (tid & 3) * 16;    // W k-chunk

    float4x acc[4];
    #pragma unroll
    for (int q = 0; q < 4; ++q)
        acc[q] = (float4x){0.f, 0.f, 0.f, 0.f};

    for (int kt = 0; kt < INF_; kt += 64) {
        __syncthreads();
        {
            float4x v = *(const float4x*)&feat[(size_t)(i0 + fr) * INF_ + kt + fc];
            uint2 u;
            u.x = cvtpk_bf16(v[0], v[1]);
            u.y = cvtpk_bf16(v[2], v[3]);
            *(uint2*)&lds_f[fr * 72 + fc] = u;
        }
        #pragma unroll
        for (int p = 0; p < 4; ++p) {
            int row = p * 64 + wr;
            const float* src = &W[(size_t)row * INF_ + kt + wc];
            float4x v0 = *(const float4x*)(src);
            float4x v1 = *(const float4x*)(src + 4);
            float4x v2 = *(const float4x*)(src + 8);
            float4x v3 = *(const float4x*)(src + 12);
            union { short8x s; unsigned int u[4]; } p0, p1;
            p0.u[0] = cvtpk_bf16(v0[0], v0[1]); p0.u[1] = cvtpk_bf16(v0[2], v0[3]);
            p0.u[2] = cvtpk_bf16(v1[0], v1[1]); p0.u[3] = cvtpk_bf16(v1[2], v1[3]);
            p1.u[0] = cvtpk_bf16(v2[0], v2[1]); p1.u[1] = cvtpk_bf16(v2[2], v2[3]);
            p1.u[2] = cvtpk_bf16(v3[0], v3[1]); p1.u[3] = cvtpk_bf16(v3[2], v3[3]);
            *(short8x*)&lds_w[row * 72 + wc]     = p0.s;
            *(short8x*)&lds_w[row * 72 + wc + 8] = p1.s;
        }
        __syncthreads();
        #pragma unroll
        for (int kk = 0; kk < 2; ++kk) {
            short8x af = *(const short8x*)&lds_f[lidx * 72 + kk * 32 + quad * 8];
            short8x bw[4];
            #pragma unroll
            for (int nt = 0; nt < 4; ++nt)
                bw[nt] = *(const short8x*)&lds_w[(w * 64 + nt * 16 + lidx) * 72 + kk * 32 + quad * 8];
            #pragma unroll
            for (int nt = 0; nt < 4; ++nt)
                acc[nt] = __builtin_amdgcn_mfma_f32_16x16x32_bf16(af, bw[nt], acc[nt], 0, 0, 0);
        }
    }
    // ---- hTf write (B-fragment-major; wave-contiguous 512B per nt) ----
    {
        const int ib    = i0 + quad * 4;      // h row base held by this thread
        const int kb2   = ib >> 5;
        const int quadB = (ib >> 3) & 3;
        const int e     = ib & 7;             // 0 or 4
        #pragma unroll
        for (int nt = 0; nt < 4; ++nt) {
            int n16 = w * 4 + nt;
            uint2 u;
            u.x = cvtpk_bf16(acc[nt][0], acc[nt][1]);
            u.y = cvtpk_bf16(acc[nt][2], acc[nt][3]);
            *(uint2*)&hTf[((size_t)(n16 * 128 + kb2) * 64 + quadB * 16 + lidx) * 8 + e] = u;
        }
    }
    // ---- es/ed epilogue: head = w ----
    float asrc[4], adst[4];
    #pragma unroll
    for (int nt = 0; nt < 4; ++nt) {
        asrc[nt] = a[w * 2 * HDIM + nt * 16 + lidx];
        adst[nt] = a[w * 2 * HDIM + HDIM + nt * 16 + lidx];
    }
    #pragma unroll
    for (int r = 0; r < 4; ++r) {
        float s = 0.f, d = 0.f;
        #pragma unroll
        for (int nt = 0; nt < 4; ++nt) {
            s += acc[nt][r] * asrc[nt];
            d += acc[nt][r] * adst[nt];
        }
        #pragma unroll
        for (int off = 1; off < 16; off <<= 1) {
            s += __shfl_xor(s, off);
            d += __shfl_xor(d, off);
        }
        if (lidx == 0) {
            int row = i0 + quad * 4 + r;
            es[row * NHEAD + w] = s;
            Bt[row * NHEAD + w] = f2bf(__expf(d));
            Dt[row * NHEAD + w] = f2bf(__expf(0.2f * d));
        }
    }
}

// ============================================================
// K2: fused den + attn-row write. 1 row/block, 4096 blocks.
// Mask from precomputed bitmask (one coalesced ushort/thread).
// Pass 1 keeps masked per-head terms in registers; pass 2 is a
// pure register dot.
// ============================================================
__global__ __launch_bounds__(256) void k_attn(const unsigned short* __restrict__ mask,
                                              const float* __restrict__ es,
                                              const unsigned short* __restrict__ Bt,
                                              const unsigned short* __restrict__ Dt,
                                              unsigned short* __restrict__ attn) {
    __shared__ float red[4][4];
    __shared__ float cfs[4];
    const int tid = threadIdx.x;
    const int wv  = tid >> 6;
    const int lane = tid & 63;
    const int i = blockIdx.x;

    const float4x esv = ((const float4x*)es)[i];
    float2x A01, A23, C01, C23;
    A01[0] = __expf(esv[0]); A01[1] = __expf(esv[1]);
    A23[0] = __expf(esv[2]); A23[1] = __expf(esv[3]);
    C01[0] = __expf(0.2f * esv[0]); C01[1] = __expf(0.2f * esv[1]);
    C23[0] = __expf(0.2f * esv[2]); C23[1] = __expf(0.2f * esv[3]);

    const unsigned int mbits = mask[(size_t)i * 256 + tid];
    const uint4* B4 = (const uint4*)Bt;
    const uint4* D4 = (const uint4*)Dt;

    // ---- pass 1: masked per-head terms -> registers; accumulate den ----
    float2x m01[4][4], m23[4][4];
    float2x den01 = (float2x){0.f, 0.f};
    float2x den23 = (float2x){0.f, 0.f};
    #pragma unroll
    for (int t = 0; t < 4; ++t) {
        int jv = t * 256 + tid;
        uint4 bu0 = B4[jv * 2], bu1 = B4[jv * 2 + 1];
        uint4 du0 = D4[jv * 2], du1 = D4[jv * 2 + 1];
        unsigned int bwv[8] = {bu0.x, bu0.y, bu0.z, bu0.w, bu1.x, bu1.y, bu1.z, bu1.w};
        unsigned int dwv[8] = {du0.x, du0.y, du0.z, du0.w, du1.x, du1.y, du1.z, du1.w};
        #pragma unroll
        for (int u = 0; u < 4; ++u) {
            float2x b01 = bf2up(bwv[u * 2]);
            float2x b23 = bf2up(bwv[u * 2 + 1]);
            float2x d01 = bf2up(dwv[u * 2]);
            float2x d23 = bf2up(dwv[u * 2 + 1]);
            float mf = (mbits & (1u << (t * 4 + u))) ? 1.f : 0.f;
            float2x mf2; mf2[0] = mf; mf2[1] = mf;
            m01[t][u] = mf2 * max2(A01 * b01, C01 * d01);
            m23[t][u] = mf2 * max2(A23 * b23, C23 * d23);
            den01 += m01[t][u];
            den23 += m23[t][u];
        }
    }
    float dh[4] = {den01[0], den01[1], den23[0], den23[1]};
    #pragma unroll
    for (int off = 1; off < 64; off <<= 1) {
        #pragma unroll
        for (int h = 0; h < 4; ++h)
            dh[h] += __shfl_xor(dh[h], off);
    }
    if (lane == 0) {
        #pragma unroll
        for (int h = 0; h < 4; ++h) red[wv][h] = dh[h];
    }
    __syncthreads();
    if (tid < 4)
        cfs[tid] = red[0][tid] + red[1][tid] + red[2][tid] + red[3][tid];
    __syncthreads();
    float sc[4];
    #pragma unroll
    for (int h = 0; h < 4; ++h) {
        float den = cfs[h];
        sc[h] = den > 0.f ? 0.25f / den : 0.f;
    }

    // ---- pass 2: pure register dot, cvt_pk pack, store ----
    unsigned short* orow = attn + (size_t)i * NN;
    #pragma unroll
    for (int t = 0; t < 4; ++t) {
        int jv = t * 256 + tid;
        float pv[4];
        #pragma unroll
        for (int u = 0; u < 4; ++u) {
            pv[u] = sc[0] * m01[t][u][0] + sc[1] * m01[t][u][1]
                  + sc[2] * m23[t][u][0] + sc[3] * m23[t][u][1];
        }
        uint2 o;
        o.x = cvtpk_bf16(pv[0], pv[1]);
        o.y = cvtpk_bf16(pv[2], pv[3]);
        *(uint2*)&orow[jv * 4] = o;
    }
}

// ============================================================
// K3: split-K GEMM. A (attn) staged via DOUBLE-BUFFERED tiny LDS
// (2 x 4.6 KB) -- ONE barrier per k-step (was 2): ds_write of the
// next step's tile goes to the idle buffer before the MFMA phase;
// the end-of-step barrier orders write(cur^1) vs next reads AND
// reads(cur) vs the following write. A-load issued a full step
// ahead. B direct from fragment-major hTf (1KB/wave, L2). Grid
// (KSPLIT, 128): linear wgid % 8 == k-slice -> each XCD's blocks
// share one 256KiB hTf slice + 4MiB attn slice (fits XCD L2).
// ============================================================
__global__ __launch_bounds__(256) void k_out_gemm(const unsigned short* __restrict__ attn,
                                                  const unsigned short* __restrict__ hTf,
                                                  float* __restrict__ out) {
    __shared__ __align__(16) unsigned short lds_a[2][32 * 72];
    const int tid  = threadIdx.x;
    const int w    = tid >> 6;
    const int lane = tid & 63;
    const int lidx = lane & 15;
    const int quad = lane >> 4;
    const int i0    = blockIdx.y * 32;
    const int kbase = blockIdx.x * (NN / KSPLIT);   // 512-wide k slice
    const int kbb   = kbase >> 5;                   // base 32-k block index
    const int sr   = tid >> 3;          // stage row 0..31
    const int sc   = (tid & 7) * 8;     // stage chunk (shorts)

    float4x acc[2][4];
    #pragma unroll
    for (int p = 0; p < 2; ++p)
        #pragma unroll
        for (int q = 0; q < 4; ++q)
            acc[p][q] = (float4x){0.f, 0.f, 0.f, 0.f};

    const unsigned short* arow = &attn[(size_t)(i0 + sr) * NN + kbase + sc];

    // ---- prologue: stage step 0, prefetch step 1 ----
    short8x pa;
    pa = *(const short8x*)(arow);
    *(short8x*)&lds_a[0][sr * 72 + sc] = pa;
    pa = *(const short8x*)(arow + 64);
    __syncthreads();

    const int KSTEPS = (NN / KSPLIT) / 64;   // 8
    #pragma unroll
    for (int ks = 0; ks < KSTEPS; ++ks) {
        const int cur = ks & 1;
        if (ks + 1 < KSTEPS)
            *(short8x*)&lds_a[cur ^ 1][sr * 72 + sc] = pa;   // next tile -> idle buffer
        if (ks + 2 < KSTEPS)
            pa = *(const short8x*)(arow + (ks + 2) * 64);    // load 1 step ahead
        #pragma unroll
        for (int kk = 0; kk < 2; ++kk) {
            const int kb2 = kbb + ks * 2 + kk;
            short8x af[2], bfr[4];
            #pragma unroll
            for (int it = 0; it < 2; ++it)
                af[it]  = *(const short8x*)&lds_a[cur][(it * 16 + lidx) * 72 + kk * 32 + quad * 8];
            #pragma unroll
            for (int nt = 0; nt < 4; ++nt)
                bfr[nt] = *(const short8x*)&hTf[((size_t)((w * 4 + nt) * 128 + kb2) * 64 + lane) * 8];
            #pragma unroll
            for (int it = 0; it < 2; ++it)
                #pragma unroll
                for (int nt = 0; nt < 4; ++nt)
                    acc[it][nt] = __builtin_amdgcn_mfma_f32_16x16x32_bf16(
                        af[it], bfr[nt], acc[it][nt], 0, 0, 0);
        }
        __syncthreads();
    }
    #pragma unroll
    for (int it = 0; it < 2; ++it)
        #pragma unroll
        for (int nt = 0; nt < 4; ++nt)
            #pragma unroll
            for (int rr = 0; rr < 4; ++rr) {
                int row = i0 + it * 16 + quad * 4 + rr;
                int col = w * 64 + nt * 16 + lidx;
                unsafeAtomicAdd(&out[(size_t)row * OUTF + col], acc[it][nt][rr]);
            }
}

// ============================================================
extern "C" void kernel_launch(void* const* d_in, const int* in_sizes, int n_in,
                              void* d_out, int out_size, void* d_ws, size_t ws_size,
                              hipStream_t stream) {
    const float* feat = (const float*)d_in[0];   // [4096,512]
    const float* adj  = (const float*)d_in[1];   // [4096,4096]
    const float* W    = (const float*)d_in[2];   // [256,512]
    const float* a    = (const float*)d_in[3];   // [4,128]
    const float* bias = (const float*)d_in[4];   // [256]
    float* out = (float*)d_out;                  // [4096,256] fp32

    char* ws = (char*)d_ws;
    float*          es    = (float*)(ws + 0);                        // 64 KiB
    unsigned short* Btb   = (unsigned short*)(ws + (64u << 10));     // 32 KiB
    unsigned short* Dtb   = (unsigned short*)(ws + (96u << 10));     // 32 KiB
    unsigned short* mask  = (unsigned short*)(ws + (128u << 10));    // 2 MiB
    unsigned short* hTf   = (unsigned short*)(ws + (2560u << 10));   // 2 MiB
    unsigned short* attn  = (unsigned short*)(ws + (5120u << 10));   // 32 MiB

    k_hedge    <<<2304,              256, 0, stream>>>(feat, W, a, bias, adj, hTf, es, Btb, Dtb, mask, out);
    k_attn     <<<NN,                256, 0, stream>>>(mask, es, Btb, Dtb, attn);
    k_out_gemm <<<dim3(KSPLIT, 128), 256, 0, stream>>>(attn, hTf, out);
}

// Round 15
// 166.254 us; speedup vs baseline: 1.0159x; 1.0159x over previous
//
#include <hip/hip_runtime.h>
#include <math.h>

// ---- problem constants ----
#define NN      4096   // nodes
#define INF_    512    // in features
#define OUTF    256    // out features
#define NHEAD   4
#define HDIM    64
#define KSPLIT  8

typedef __attribute__((ext_vector_type(8))) short  short8x;
typedef __attribute__((ext_vector_type(4))) float  float4x;
typedef __attribute__((ext_vector_type(2))) float  float2x;

__device__ __forceinline__ unsigned short f2bf(float x) {
    union { float f; unsigned int u; } c; c.f = x;
    unsigned int r = (c.u + 0x7FFFu + ((c.u >> 16) & 1u)) >> 16;
    return (unsigned short)r;
}
// pack 2 fp32 -> 2 bf16 in one dword (RNE, identical to f2bf)
__device__ __forceinline__ unsigned int cvtpk_bf16(float lo, float hi) {
    unsigned int r;
    asm("v_cvt_pk_bf16_f32 %0, %1, %2" : "=v"(r) : "v"(lo), "v"(hi));
    return r;
}
// unpack a bf16 pair (one dword) into float2 {lo, hi}
__device__ __forceinline__ float2x bf2up(unsigned int u) {
    union { unsigned int x; float f; } lo, hi;
    lo.x = u << 16; hi.x = u & 0xFFFF0000u;
    float2x r; r[0] = lo.f; r[1] = hi.f; return r;
}
__device__ __forceinline__ float2x max2(float2x a, float2x b) {
    float2x r; r[0] = fmaxf(a[0], b[0]); r[1] = fmaxf(a[1], b[1]); return r;
}

// ============================================================
// K1: blocks 0..255: h = feat @ W^T (fp32 converted in-register),
// 16-row tiles, BK=64, pitch 72; bias-inits the block's out slab.
// hT is written in B-FRAGMENT-MAJOR layout hTf:
//   short idx = ((n16*128 + kb2)*64 + quadB*16 + lidx)*8 + e
// so k_out_gemm's B loads are 1KB-contiguous per wave (no LDS).
// Epilogue also writes es/Bt/Dt.
// Blocks 256..2303: adj -> 16-bit masks (2 rows/block), packed in
// k_attn's consumption order. adj read exactly ONCE per launch.
// ============================================================
__global__ __launch_bounds__(256) void k_hedge(const float* __restrict__ feat,
                                               const float* __restrict__ W,
                                               const float* __restrict__ a,
                                               const float* __restrict__ bias,
                                               const float* __restrict__ adj,
                                               unsigned short* __restrict__ hTf,
                                               float* __restrict__ es,
                                               unsigned short* __restrict__ Bt,
                                               unsigned short* __restrict__ Dt,
                                               unsigned short* __restrict__ mask,
                                               float* __restrict__ out) {
    __shared__ __align__(16) unsigned short lds_f[16 * 72];
    __shared__ __align__(16) unsigned short lds_w[256 * 72];
    const int tid  = threadIdx.x;

    if (blockIdx.x >= 256) {
        // ---- mask production: 2 adj rows per block, coalesced ----
        const int mb = blockIdx.x - 256;        // 0..2047
        #pragma unroll
        for (int r = 0; r < 2; ++r) {
            const int row = mb * 2 + r;
            const float4x* arow4 = (const float4x*)(adj + (size_t)row * NN);
            unsigned int bits = 0;
            #pragma unroll
            for (int t = 0; t < 4; ++t) {
                float4x av = arow4[t * 256 + tid];
                #pragma unroll
                for (int e = 0; e < 4; ++e)
                    bits |= (av[e] > 0.1f ? 1u : 0u) << (t * 4 + e);
            }
            mask[(size_t)row * 256 + tid] = (unsigned short)bits;
        }
        return;
    }

    const int w    = tid >> 6;
    const int lane = tid & 63;
    const int lidx = lane & 15;
    const int quad = lane >> 4;
    const int i0   = blockIdx.x * 16;

    // ---- bias-init out rows i0..i0+15 (4096 floats, coalesced) ----
    {
        float4x bv = *(const float4x*)(bias + ((tid * 4) & 255));
        float* ob = out + (size_t)i0 * OUTF;
        #pragma unroll
        for (int itr = 0; itr < 4; ++itr)
            *(float4x*)(ob + itr * 1024 + tid * 4) = bv;
    }

    const int fr = tid >> 4;          // feat row 0..15
    const int fc = (tid & 15) * 4;    // feat k-chunk
    const int wr = tid >> 2;          // W row-within-group 0..63
    const int wc = (tid & 3) * 16;    // W k-chunk

    float4x acc[4];
    #pragma unroll
    for (int q = 0; q < 4; ++q)
        acc[q] = (float4x){0.f, 0.f, 0.f, 0.f};

    for (int kt = 0; kt < INF_; kt += 64) {
        __syncthreads();
        {
            float4x v = *(const float4x*)&feat[(size_t)(i0 + fr) * INF_ + kt + fc];
            uint2 u;
            u.x = cvtpk_bf16(v[0], v[1]);
            u.y = cvtpk_bf16(v[2], v[3]);
            *(uint2*)&lds_f[fr * 72 + fc] = u;
        }
        #pragma unroll
        for (int p = 0; p < 4; ++p) {
            int row = p * 64 + wr;
            const float* src = &W[(size_t)row * INF_ + kt + wc];
            float4x v0 = *(const float4x*)(src);
            float4x v1 = *(const float4x*)(src + 4);
            float4x v2 = *(const float4x*)(src + 8);
            float4x v3 = *(const float4x*)(src + 12);
            union { short8x s; unsigned int u[4]; } p0, p1;
            p0.u[0] = cvtpk_bf16(v0[0], v0[1]); p0.u[1] = cvtpk_bf16(v0[2], v0[3]);
            p0.u[2] = cvtpk_bf16(v1[0], v1[1]); p0.u[3] = cvtpk_bf16(v1[2], v1[3]);
            p1.u[0] = cvtpk_bf16(v2[0], v2[1]); p1.u[1] = cvtpk_bf16(v2[2], v2[3]);
            p1.u[2] = cvtpk_bf16(v3[0], v3[1]); p1.u[3] = cvtpk_bf16(v3[2], v3[3]);
            *(short8x*)&lds_w[row * 72 + wc]     = p0.s;
            *(short8x*)&lds_w[row * 72 + wc + 8] = p1.s;
        }
        __syncthreads();
        #pragma unroll
        for (int kk = 0; kk < 2; ++kk) {
            short8x af = *(const short8x*)&lds_f[lidx * 72 + kk * 32 + quad * 8];
            short8x bw[4];
            #pragma unroll
            for (int nt = 0; nt < 4; ++nt)
                bw[nt] = *(const short8x*)&lds_w[(w * 64 + nt * 16 + lidx) * 72 + kk * 32 + quad * 8];
            #pragma unroll
            for (int nt = 0; nt < 4; ++nt)
                acc[nt] = __builtin_amdgcn_mfma_f32_16x16x32_bf16(af, bw[nt], acc[nt], 0, 0, 0);
        }
    }
    // ---- hTf write (B-fragment-major; wave-contiguous 512B per nt) ----
    {
        const int ib    = i0 + quad * 4;      // h row base held by this thread
        const int kb2   = ib >> 5;
        const int quadB = (ib >> 3) & 3;
        const int e     = ib & 7;             // 0 or 4
        #pragma unroll
        for (int nt = 0; nt < 4; ++nt) {
            int n16 = w * 4 + nt;
            uint2 u;
            u.x = cvtpk_bf16(acc[nt][0], acc[nt][1]);
            u.y = cvtpk_bf16(acc[nt][2], acc[nt][3]);
            *(uint2*)&hTf[((size_t)(n16 * 128 + kb2) * 64 + quadB * 16 + lidx) * 8 + e] = u;
        }
    }
    // ---- es/ed epilogue: head = w ----
    float asrc[4], adst[4];
    #pragma unroll
    for (int nt = 0; nt < 4; ++nt) {
        asrc[nt] = a[w * 2 * HDIM + nt * 16 + lidx];
        adst[nt] = a[w * 2 * HDIM + HDIM + nt * 16 + lidx];
    }
    #pragma unroll
    for (int r = 0; r < 4; ++r) {
        float s = 0.f, d = 0.f;
        #pragma unroll
        for (int nt = 0; nt < 4; ++nt) {
            s += acc[nt][r] * asrc[nt];
            d += acc[nt][r] * adst[nt];
        }
        #pragma unroll
        for (int off = 1; off < 16; off <<= 1) {
            s += __shfl_xor(s, off);
            d += __shfl_xor(d, off);
        }
        if (lidx == 0) {
            int row = i0 + quad * 4 + r;
            es[row * NHEAD + w] = s;
            Bt[row * NHEAD + w] = f2bf(__expf(d));
            Dt[row * NHEAD + w] = f2bf(__expf(0.2f * d));
        }
    }
}

// ============================================================
// K2: fused den + attn-row write, TWO ROWS PER BLOCK (2048
// blocks). The Bt/Dt tables are row-independent: both rows share
// every table load and every unpack. Raw packed table words kept
// in registers (bw/dw: 64 dwords) -- pass 2 recomputes the
// max-terms from registers (bit-identical arithmetic), instead of
// holding 128 f32 m-terms (which would halve occupancy).
// Per row: loads halved, VALU unchanged, fixed costs halved.
// ============================================================
__global__ __launch_bounds__(256) void k_attn(const unsigned short* __restrict__ mask,
                                              const float* __restrict__ es,
                                              const unsigned short* __restrict__ Bt,
                                              const unsigned short* __restrict__ Dt,
                                              unsigned short* __restrict__ attn) {
    __shared__ float red[4][8];
    __shared__ float cfs[8];
    const int tid = threadIdx.x;
    const int wv  = tid >> 6;
    const int lane = tid & 63;
    const int i0 = blockIdx.x * 2;

    const float4x esv0 = ((const float4x*)es)[i0];
    const float4x esv1 = ((const float4x*)es)[i0 + 1];
    float2x A0a, A0b, C0a, C0b, A1a, A1b, C1a, C1b;
    A0a[0] = __expf(esv0[0]); A0a[1] = __expf(esv0[1]);
    A0b[0] = __expf(esv0[2]); A0b[1] = __expf(esv0[3]);
    C0a[0] = __expf(0.2f * esv0[0]); C0a[1] = __expf(0.2f * esv0[1]);
    C0b[0] = __expf(0.2f * esv0[2]); C0b[1] = __expf(0.2f * esv0[3]);
    A1a[0] = __expf(esv1[0]); A1a[1] = __expf(esv1[1]);
    A1b[0] = __expf(esv1[2]); A1b[1] = __expf(esv1[3]);
    C1a[0] = __expf(0.2f * esv1[0]); C1a[1] = __expf(0.2f * esv1[1]);
    C1b[0] = __expf(0.2f * esv1[2]); C1b[1] = __expf(0.2f * esv1[3]);

    const unsigned int mb0 = mask[(size_t)i0 * 256 + tid];
    const unsigned int mb1 = mask[(size_t)(i0 + 1) * 256 + tid];
    const uint4* B4 = (const uint4*)Bt;
    const uint4* D4 = (const uint4*)Dt;

    // ---- load ALL table words into registers (shared by both rows) ----
    unsigned int bw[4][8], dw[4][8];
    #pragma unroll
    for (int t = 0; t < 4; ++t) {
        int jv = t * 256 + tid;
        uint4 bu0 = B4[jv * 2], bu1 = B4[jv * 2 + 1];
        uint4 du0 = D4[jv * 2], du1 = D4[jv * 2 + 1];
        bw[t][0] = bu0.x; bw[t][1] = bu0.y; bw[t][2] = bu0.z; bw[t][3] = bu0.w;
        bw[t][4] = bu1.x; bw[t][5] = bu1.y; bw[t][6] = bu1.z; bw[t][7] = bu1.w;
        dw[t][0] = du0.x; dw[t][1] = du0.y; dw[t][2] = du0.z; dw[t][3] = du0.w;
        dw[t][4] = du1.x; dw[t][5] = du1.y; dw[t][6] = du1.z; dw[t][7] = du1.w;
    }

    // ---- pass 1: den for both rows (shared unpack) ----
    float2x d0a = (float2x){0.f, 0.f}, d0b = (float2x){0.f, 0.f};
    float2x d1a = (float2x){0.f, 0.f}, d1b = (float2x){0.f, 0.f};
    #pragma unroll
    for (int t = 0; t < 4; ++t) {
        #pragma unroll
        for (int u = 0; u < 4; ++u) {
            float2x b01 = bf2up(bw[t][u * 2]);
            float2x b23 = bf2up(bw[t][u * 2 + 1]);
            float2x q01 = bf2up(dw[t][u * 2]);
            float2x q23 = bf2up(dw[t][u * 2 + 1]);
            float f0 = (mb0 & (1u << (t * 4 + u))) ? 1.f : 0.f;
            float f1 = (mb1 & (1u << (t * 4 + u))) ? 1.f : 0.f;
            float2x f0v; f0v[0] = f0; f0v[1] = f0;
            float2x f1v; f1v[0] = f1; f1v[1] = f1;
            d0a += f0v * max2(A0a * b01, C0a * q01);
            d0b += f0v * max2(A0b * b23, C0b * q23);
            d1a += f1v * max2(A1a * b01, C1a * q01);
            d1b += f1v * max2(A1b * b23, C1b * q23);
        }
    }
    float dh[8] = {d0a[0], d0a[1], d0b[0], d0b[1], d1a[0], d1a[1], d1b[0], d1b[1]};
    #pragma unroll
    for (int off = 1; off < 64; off <<= 1) {
        #pragma unroll
        for (int h = 0; h < 8; ++h)
            dh[h] += __shfl_xor(dh[h], off);
    }
    if (lane == 0) {
        #pragma unroll
        for (int h = 0; h < 8; ++h) red[wv][h] = dh[h];
    }
    __syncthreads();
    if (tid < 8)
        cfs[tid] = red[0][tid] + red[1][tid] + red[2][tid] + red[3][tid];
    __syncthreads();
    float sc0[4], sc1[4];
    #pragma unroll
    for (int h = 0; h < 4; ++h) {
        float e0 = cfs[h],     e1 = cfs[4 + h];
        sc0[h] = e0 > 0.f ? 0.25f / e0 : 0.f;
        sc1[h] = e1 > 0.f ? 0.25f / e1 : 0.f;
    }

    // ---- pass 2: recompute from registers, store both rows ----
    unsigned short* o0 = attn + (size_t)i0 * NN;
    unsigned short* o1 = attn + (size_t)(i0 + 1) * NN;
    #pragma unroll
    for (int t = 0; t < 4; ++t) {
        int jv = t * 256 + tid;
        float p0[4], p1[4];
        #pragma unroll
        for (int u = 0; u < 4; ++u) {
            float2x b01 = bf2up(bw[t][u * 2]);
            float2x b23 = bf2up(bw[t][u * 2 + 1]);
            float2x q01 = bf2up(dw[t][u * 2]);
            float2x q23 = bf2up(dw[t][u * 2 + 1]);
            float2x t0a = max2(A0a * b01, C0a * q01);
            float2x t0b = max2(A0b * b23, C0b * q23);
            float2x t1a = max2(A1a * b01, C1a * q01);
            float2x t1b = max2(A1b * b23, C1b * q23);
            float s0 = sc0[0] * t0a[0] + sc0[1] * t0a[1] + sc0[2] * t0b[0] + sc0[3] * t0b[1];
            float s1 = sc1[0] * t1a[0] + sc1[1] * t1a[1] + sc1[2] * t1b[0] + sc1[3] * t1b[1];
            p0[u] = (mb0 & (1u << (t * 4 + u))) ? s0 : 0.f;
            p1[u] = (mb1 & (1u << (t * 4 + u))) ? s1 : 0.f;
        }
        uint2 w0, w1;
        w0.x = cvtpk_bf16(p0[0], p0[1]); w0.y = cvtpk_bf16(p0[2], p0[3]);
        w1.x = cvtpk_bf16(p1[0], p1[1]); w1.y = cvtpk_bf16(p1[2], p1[3]);
        *(uint2*)&o0[jv * 4] = w0;
        *(uint2*)&o1[jv * 4] = w1;
    }
}

// ============================================================
// K3: split-K GEMM (R14, unchanged). A double-buffered tiny LDS,
// one barrier/step; B direct from fragment-major hTf (1KB/wave,
// L2). Grid (KSPLIT, 128): wgid%8 == k-slice for XCD L2 locality.
// ============================================================
__global__ __launch_bounds__(256) void k_out_gemm(const unsigned short* __restrict__ attn,
                                                  const unsigned short* __restrict__ hTf,
                                                  float* __restrict__ out) {
    __shared__ __align__(16) unsigned short lds_a[2][32 * 72];
    const int tid  = threadIdx.x;
    const int w    = tid >> 6;
    const int lane = tid & 63;
    const int lidx = lane & 15;
    const int quad = lane >> 4;
    const int i0    = blockIdx.y * 32;
    const int kbase = blockIdx.x * (NN / KSPLIT);   // 512-wide k slice
    const int kbb   = kbase >> 5;                   // base 32-k block index
    const int sr   = tid >> 3;          // stage row 0..31
    const int sc   = (tid & 7) * 8;     // stage chunk (shorts)

    float4x acc[2][4];
    #pragma unroll
    for (int p = 0; p < 2; ++p)
        #pragma unroll
        for (int q = 0; q < 4; ++q)
            acc[p][q] = (float4x){0.f, 0.f, 0.f, 0.f};

    const unsigned short* arow = &attn[(size_t)(i0 + sr) * NN + kbase + sc];

    // ---- prologue: stage step 0, prefetch step 1 ----
    short8x pa;
    pa = *(const short8x*)(arow);
    *(short8x*)&lds_a[0][sr * 72 + sc] = pa;
    pa = *(const short8x*)(arow + 64);
    __syncthreads();

    const int KSTEPS = (NN / KSPLIT) / 64;   // 8
    #pragma unroll
    for (int ks = 0; ks < KSTEPS; ++ks) {
        const int cur = ks & 1;
        if (ks + 1 < KSTEPS)
            *(short8x*)&lds_a[cur ^ 1][sr * 72 + sc] = pa;   // next tile -> idle buffer
        if (ks + 2 < KSTEPS)
            pa = *(const short8x*)(arow + (ks + 2) * 64);    // load 1 step ahead
        #pragma unroll
        for (int kk = 0; kk < 2; ++kk) {
            const int kb2 = kbb + ks * 2 + kk;
            short8x af[2], bfr[4];
            #pragma unroll
            for (int it = 0; it < 2; ++it)
                af[it]  = *(const short8x*)&lds_a[cur][(it * 16 + lidx) * 72 + kk * 32 + quad * 8];
            #pragma unroll
            for (int nt = 0; nt < 4; ++nt)
                bfr[nt] = *(const short8x*)&hTf[((size_t)((w * 4 + nt) * 128 + kb2) * 64 + lane) * 8];
            #pragma unroll
            for (int it = 0; it < 2; ++it)
                #pragma unroll
                for (int nt = 0; nt < 4; ++nt)
                    acc[it][nt] = __builtin_amdgcn_mfma_f32_16x16x32_bf16(
                        af[it], bfr[nt], acc[it][nt], 0, 0, 0);
        }
        __syncthreads();
    }
    #pragma unroll
    for (int it = 0; it < 2; ++it)
        #pragma unroll
        for (int nt = 0; nt < 4; ++nt)
            #pragma unroll
            for (int rr = 0; rr < 4; ++rr) {
                int row = i0 + it * 16 + quad * 4 + rr;
                int col = w * 64 + nt * 16 + lidx;
                unsafeAtomicAdd(&out[(size_t)row * OUTF + col], acc[it][nt][rr]);
            }
}

// ============================================================
extern "C" void kernel_launch(void* const* d_in, const int* in_sizes, int n_in,
                              void* d_out, int out_size, void* d_ws, size_t ws_size,
                              hipStream_t stream) {
    const float* feat = (const float*)d_in[0];   // [4096,512]
    const float* adj  = (const float*)d_in[1];   // [4096,4096]
    const float* W    = (const float*)d_in[2];   // [256,512]
    const float* a    = (const float*)d_in[3];   // [4,128]
    const float* bias = (const float*)d_in[4];   // [256]
    float* out = (float*)d_out;                  // [4096,256] fp32

    char* ws = (char*)d_ws;
    float*          es    = (float*)(ws + 0);                        // 64 KiB
    unsigned short* Btb   = (unsigned short*)(ws + (64u << 10));     // 32 KiB
    unsigned short* Dtb   = (unsigned short*)(ws + (96u << 10));     // 32 KiB
    unsigned short* mask  = (unsigned short*)(ws + (128u << 10));    // 2 MiB
    unsigned short* hTf   = (unsigned short*)(ws + (2560u << 10));   // 2 MiB
    unsigned short* attn  = (unsigned short*)(ws + (5120u << 10));   // 32 MiB

    k_hedge    <<<2304,              256, 0, stream>>>(feat, W, a, bias, adj, hTf, es, Btb, Dtb, mask, out);
    k_attn     <<<NN / 2,            256, 0, stream>>>(mask, es, Btb, Dtb, attn);
    k_out_gemm <<<dim3(KSPLIT, 128), 256, 0, stream>>>(attn, hTf, out);
}